// Round 2
// baseline (428.885 us; speedup 1.0000x reference)
//
#include <hip/hip_runtime.h>
#include <math.h>

#define BATCH 256
#define PRE   64     // k
#define NEXT  32     // K
#define DIN   128    // d
#define DOUT  64     // D

typedef __attribute__((ext_vector_type(8))) short bf16x8;
typedef __attribute__((ext_vector_type(4))) float f32x4;

__device__ __forceinline__ unsigned short f2bf(float f) {
    unsigned u = __float_as_uint(f);
    unsigned r = (u + 0x7fffu + ((u >> 16) & 1u)) >> 16;   // RNE
    return (unsigned short)r;
}
__device__ __forceinline__ float bf2f(unsigned short h) {
    return __uint_as_float(((unsigned)h) << 16);
}

// ---------------- MFMA GEMM: p'[lb,k,*] = x[b,k,:] @ W[k,K,:,:] (split bf16) ----
// Grid (K=32, k=64, btile=chunk/128). Block 256 = 4 waves; wave covers 32 b-rows.
// No LDS: A/B fragments loaded directly from global in MFMA fragment order.
// Split precision: x = xh+xl, W = wh+wl (bf16 each); p ~= xh*wh + xl*wh + xh*wl.
// Output layout permuted for the route kernel: within each (b,k) 2048-float
// slice, float4 index = j4*64 + (K*2 + half), where D = half*32 + j4*4 + e.
__global__ __launch_bounds__(256, 2) void gemm_kernel(const float* __restrict__ x,
                                                      const float* __restrict__ W,
                                                      float* __restrict__ p,
                                                      int b0)
{
    const int K    = blockIdx.x;
    const int kk   = blockIdx.y;
    const int bt   = blockIdx.z;
    const int t    = threadIdx.x;
    const int wave = t >> 6;
    const int lane = t & 63;
    const int ln   = lane & 15;      // m for A, n for B, col for C/D
    const int quad = lane >> 4;
    const int lrow = bt * 128 + wave * 32;   // local row base within chunk

    f32x4 acc[2][4];
#pragma unroll
    for (int mt = 0; mt < 2; ++mt)
#pragma unroll
        for (int nt = 0; nt < 4; ++nt) acc[mt][nt] = (f32x4){0.f, 0.f, 0.f, 0.f};

    const float* Wk = W + (size_t)(kk * NEXT + K) * DIN * DOUT;

    for (int dc = 0; dc < 4; ++dc) {
        const int d0 = dc * 32 + quad * 8;   // A/B k-dim: quad*8 + j within chunk
        // ---- A fragments (x rows), hi/lo split ----
        bf16x8 ah[2], al[2];
#pragma unroll
        for (int mt = 0; mt < 2; ++mt) {
            const float* xa = x + ((size_t)(b0 + lrow + mt * 16 + ln) * PRE + kk) * DIN + d0;
            float4 v0 = *(const float4*)xa;
            float4 v1 = *(const float4*)(xa + 4);
            float xv[8] = {v0.x, v0.y, v0.z, v0.w, v1.x, v1.y, v1.z, v1.w};
#pragma unroll
            for (int j = 0; j < 8; ++j) {
                unsigned short h = f2bf(xv[j]);
                ah[mt][j] = (short)h;
                al[mt][j] = (short)f2bf(xv[j] - bf2f(h));
            }
        }
        // ---- B fragments (W), hi/lo split; lane reads 8 D-strided dwords ----
        bf16x8 bh[4], bl[4];
#pragma unroll
        for (int nt = 0; nt < 4; ++nt) {
            const float* wa = Wk + (size_t)d0 * DOUT + nt * 16 + ln;
#pragma unroll
            for (int j = 0; j < 8; ++j) {
                float wv = wa[(size_t)j * DOUT];
                unsigned short h = f2bf(wv);
                bh[nt][j] = (short)h;
                bl[nt][j] = (short)f2bf(wv - bf2f(h));
            }
        }
        // ---- 3-product split MFMA ----
#pragma unroll
        for (int mt = 0; mt < 2; ++mt)
#pragma unroll
            for (int nt = 0; nt < 4; ++nt) {
                acc[mt][nt] = __builtin_amdgcn_mfma_f32_16x16x32_bf16(ah[mt], bh[nt], acc[mt][nt], 0, 0, 0);
                acc[mt][nt] = __builtin_amdgcn_mfma_f32_16x16x32_bf16(al[mt], bh[nt], acc[mt][nt], 0, 0, 0);
                acc[mt][nt] = __builtin_amdgcn_mfma_f32_16x16x32_bf16(ah[mt], bl[nt], acc[mt][nt], 0, 0, 0);
            }
    }

    // ---- store, permuted layout: C/D map col=ln, row=quad*4+r ----
#pragma unroll
    for (int mt = 0; mt < 2; ++mt)
#pragma unroll
        for (int nt = 0; nt < 4; ++nt) {
            const int D = nt * 16 + ln;
            const size_t off = (size_t)((D & 31) >> 2) * 256 + (size_t)(K * 2 + (D >> 5)) * 4 + (D & 3);
#pragma unroll
            for (int r = 0; r < 4; ++r) {
                const int lb = lrow + mt * 16 + quad * 4 + r;
                p[(size_t)(lb * PRE + kk) * 2048 + off] = acc[mt][nt][r];
            }
        }
}

// ---------------- Routing: 3 fused passes over p', one block (1024 thr) per b ----
// 16 waves; wave w handles k = i*16 + w, i = 0..3. lane = K*2+half.
// Loads are fully coalesced: instr j reads 64 consecutive float4 (1 KB).
__global__ __launch_bounds__(1024, 4) void route_kernel(const float* __restrict__ p,
                                                        float* __restrict__ out,
                                                        int b0)
{
    __shared__ float qsh[64 * 33];   // [slice = K*2+half][33] padded
    const int b    = blockIdx.x;
    const int t    = threadIdx.x;
    const int wave = t >> 6;         // 0..15
    const int lane = t & 63;         // = K*2 + half
    const float4* pb4 = (const float4*)(p + (size_t)b * (PRE * NEXT * DOUT));

    float qcur[32], qacc[32], blog[4];
#pragma unroll
    for (int i = 0; i < 4; ++i) blog[i] = 0.f;

    for (int pass = 0; pass < 3; ++pass) {
        for (int i = t; i < 64 * 33; i += 1024) qsh[i] = 0.f;
#pragma unroll
        for (int j = 0; j < 32; ++j) qacc[j] = 0.f;
        __syncthreads();

        float4 pv[2][8];
        {
            const size_t base = (size_t)wave * 512;
#pragma unroll
            for (int j = 0; j < 8; ++j) pv[0][j] = pb4[base + j * 64 + lane];
        }
#pragma unroll
        for (int i = 0; i < 4; ++i) {
            const int buf = i & 1;
            if (i < 3) {
                const size_t base = (size_t)((i + 1) * 16 + wave) * 512;
#pragma unroll
                for (int j = 0; j < 8; ++j) pv[buf ^ 1][j] = pb4[base + j * 64 + lane];
            }
            float c;
            if (pass == 0) {
                c = 1.0f / 32.0f;          // softmax of zeros
            } else {
                float delta = 0.f;
#pragma unroll
                for (int j = 0; j < 8; ++j) {
                    delta += pv[buf][j].x * qcur[j * 4 + 0];
                    delta += pv[buf][j].y * qcur[j * 4 + 1];
                    delta += pv[buf][j].z * qcur[j * 4 + 2];
                    delta += pv[buf][j].w * qcur[j * 4 + 3];
                }
                delta += __shfl_xor(delta, 1);       // full dot over D=64 (pair)
                blog[i] += delta;
                float m = blog[i];
                m = fmaxf(m, __shfl_xor(m, 2));
                m = fmaxf(m, __shfl_xor(m, 4));
                m = fmaxf(m, __shfl_xor(m, 8));
                m = fmaxf(m, __shfl_xor(m, 16));
                m = fmaxf(m, __shfl_xor(m, 32));
                float e = __expf(blog[i] - m);
                float s = e;
                s += __shfl_xor(s, 2);
                s += __shfl_xor(s, 4);
                s += __shfl_xor(s, 8);
                s += __shfl_xor(s, 16);
                s += __shfl_xor(s, 32);              // sum over 32 distinct K
                c = e / s;
            }
#pragma unroll
            for (int j = 0; j < 8; ++j) {
                qacc[j * 4 + 0] += c * pv[buf][j].x;
                qacc[j * 4 + 1] += c * pv[buf][j].y;
                qacc[j * 4 + 2] += c * pv[buf][j].z;
                qacc[j * 4 + 3] += c * pv[buf][j].w;
            }
        }
        // cross-wave reduce into padded LDS (bank = (lane+j)%32, conflict-free)
#pragma unroll
        for (int j = 0; j < 32; ++j) atomicAdd(&qsh[lane * 33 + j], qacc[j]);
        __syncthreads();

        // squash per K: first 512 threads, 16 per K, 4 elems each
        if (t < 512) {
            const int Kq = t >> 4, e = t & 15;
            const int D0 = e * 4;
            const int h  = D0 >> 5, j0 = D0 & 31;
            const int sbase = (Kq * 2 + h) * 33 + j0;
            float v0 = qsh[sbase + 0];
            float v1 = qsh[sbase + 1];
            float v2 = qsh[sbase + 2];
            float v3 = qsh[sbase + 3];
            float s2 = v0 * v0 + v1 * v1 + v2 * v2 + v3 * v3;
            s2 += __shfl_xor(s2, 1);
            s2 += __shfl_xor(s2, 2);
            s2 += __shfl_xor(s2, 4);
            s2 += __shfl_xor(s2, 8);
            float f = s2 / ((1.f + s2) * sqrtf(s2 + 1e-8f));
            v0 *= f; v1 *= f; v2 *= f; v3 *= f;
            if (pass < 2) {
                qsh[sbase + 0] = v0;
                qsh[sbase + 1] = v1;
                qsh[sbase + 2] = v2;
                qsh[sbase + 3] = v3;
            } else {
                float4 v = {v0, v1, v2, v3};
                ((float4*)out)[(size_t)(b0 + b) * 512 + Kq * 16 + e] = v;
            }
        }
        if (pass < 2) {
            __syncthreads();
#pragma unroll
            for (int j = 0; j < 32; ++j) qcur[j] = qsh[lane * 33 + j];
            __syncthreads();   // protect qsh before next-pass zeroing
        }
    }
}

extern "C" void kernel_launch(void* const* d_in, const int* in_sizes, int n_in,
                              void* d_out, int out_size, void* d_ws, size_t ws_size,
                              hipStream_t stream) {
    const float* x = (const float*)d_in[0];
    const float* W = (const float*)d_in[1];
    float* out = (float*)d_out;
    float* p   = (float*)d_ws;

    const size_t per_b = (size_t)PRE * NEXT * DOUT * sizeof(float);  // 512 KB
    int chunk = (ws_size >= per_b * BATCH) ? BATCH : 128;

    for (int b0 = 0; b0 < BATCH; b0 += chunk) {
        dim3 g1(NEXT, PRE, chunk / 128);
        gemm_kernel<<<g1, 256, 0, stream>>>(x, W, p, b0);
        route_kernel<<<chunk, 1024, 0, stream>>>(p, out, b0);
    }
}